// Round 1
// 180.093 us; speedup vs baseline: 1.0011x; 1.0011x over previous
//
#include <hip/hip_runtime.h>
#include <hip/hip_bf16.h>
#include <cstdint>

#define B_  2
#define S_  2048
#define D_  1024
#define H_  16
#define HD_ 64
#define M_  (B_ * S_)   // 4096
static constexpr float SC_LOG2E = 0.125f * 1.44269504088896f;  // SCALE * log2(e), folded into Q

typedef __bf16 bf16x8 __attribute__((ext_vector_type(8)));
typedef __bf16 bf16x4 __attribute__((ext_vector_type(4)));
typedef float  f32x4  __attribute__((ext_vector_type(4)));

__device__ __forceinline__ unsigned short f2b(float f) {
  union { float f; unsigned u; } x; x.f = f;
  unsigned r = x.u + 0x7FFF + ((x.u >> 16) & 1);   // RNE
  return (unsigned short)(r >> 16);
}

// async global->LDS, 16B per lane; HW uses wave-uniform LDS base + lane*16
__device__ __forceinline__ void gl_lds16(const unsigned short* g, unsigned short* l) {
  __builtin_amdgcn_global_load_lds((const __attribute__((address_space(1))) void*)g,
                                   (__attribute__((address_space(3))) void*)l, 16, 0, 0);
}

// Barriers that do NOT drain vmcnt(0) (unlike __syncthreads) — keep global loads in flight.
__device__ __forceinline__ void bar_lgkm() {   // LDS-producer barrier (ds_write staging)
  asm volatile("s_waitcnt lgkmcnt(0)\n\ts_barrier" ::: "memory");
}
__device__ __forceinline__ void bar_vm2() {    // retire all but 2 newest vmem (AITER-style)
  asm volatile("s_waitcnt vmcnt(2) lgkmcnt(0)\n\ts_barrier" ::: "memory");
}
__device__ __forceinline__ void bar_vm0() {    // full drain (last iteration)
  asm volatile("s_waitcnt vmcnt(0) lgkmcnt(0)\n\ts_barrier" ::: "memory");
}

// ------------------------------------------- fused cvt: z<4 -> transpose+cvt W, z==4 -> cvt x
__global__ void cvt_all_kernel(const float* __restrict__ x,
                               const float* __restrict__ w0, const float* __restrict__ w1,
                               const float* __restrict__ w2, const float* __restrict__ w3,
                               unsigned short* __restrict__ xb,
                               unsigned short* __restrict__ o0, unsigned short* __restrict__ o1,
                               unsigned short* __restrict__ o2, unsigned short* __restrict__ o3) {
  int tx = threadIdx.x, ty = threadIdx.y;
  if (blockIdx.z == 4) {
    int tid = ty * 32 + tx;
    int base = ((int)blockIdx.y * 32 + (int)blockIdx.x) * 1024 + tid;  // f4 index
    const float4* xf = (const float4*)x;
    ushort4* ob = (ushort4*)xb;
#pragma unroll
    for (int j = 0; j < 4; j++) {
      float4 v = xf[base + j * 256];
      ushort4 r;
      r.x = f2b(v.x); r.y = f2b(v.y); r.z = f2b(v.z); r.w = f2b(v.w);
      ob[base + j * 256] = r;
    }
    return;
  }
  const float* w = blockIdx.z == 0 ? w0 : blockIdx.z == 1 ? w1 : blockIdx.z == 2 ? w2 : w3;
  unsigned short* o = blockIdx.z == 0 ? o0 : blockIdx.z == 1 ? o1 : blockIdx.z == 2 ? o2 : o3;
  __shared__ float t[32][33];
  int x0 = blockIdx.x * 32, y0 = blockIdx.y * 32;
#pragma unroll
  for (int j = 0; j < 4; j++)
    t[ty + j * 8][tx] = w[(size_t)(y0 + ty + j * 8) * D_ + x0 + tx];
  __syncthreads();
#pragma unroll
  for (int j = 0; j < 4; j++)
    o[(size_t)(x0 + ty + j * 8) * D_ + y0 + tx] = f2b(t[tx][ty + j * 8]);
}

// ---------------------------------------------------------------- QKV GEMM
// 512 threads = 8 waves (2x4 wave grid, wave tile 64x32); 128x128 block tile, BK=32.
// TRIPLE-buffered global_load_lds staging; barrier = s_waitcnt vmcnt(2) (not 0!).
__global__ __launch_bounds__(512) void qkv_gemm_kernel(
    const unsigned short* __restrict__ xb,
    const unsigned short* __restrict__ wqt, const unsigned short* __restrict__ wkt,
    const unsigned short* __restrict__ wvt,
    const float* __restrict__ bq, const float* __restrict__ bk, const float* __restrict__ bv,
    unsigned short* __restrict__ qo, unsigned short* __restrict__ ko, unsigned short* __restrict__ vo) {
  const unsigned short* wt = blockIdx.z == 0 ? wqt : blockIdx.z == 1 ? wkt : wvt;
  const float* bias        = blockIdx.z == 0 ? bq  : blockIdx.z == 1 ? bk  : bv;
  unsigned short* out      = blockIdx.z == 0 ? qo  : blockIdx.z == 1 ? ko  : vo;
  const float scl = blockIdx.z == 0 ? SC_LOG2E : 1.0f;

  __shared__ __align__(16) unsigned short smem[6 * 4096];   // 48 KB
  const int tid = threadIdx.x;
  const int lane = tid & 63, wid = tid >> 6;
  const int wm = wid & 1, wn = wid >> 1;          // 2 x 4 wave grid
  const int m0 = blockIdx.x * 128, n0 = blockIdx.y * 128;
  const int l15 = lane & 15, q4 = lane >> 4;
  const int srow = tid >> 2, skc = (tid & 3) * 8; // staging slot: 512 chunks, 1/thread

  f32x4 zero = {0.f, 0.f, 0.f, 0.f};
  f32x4 acc[4][2];
#pragma unroll
  for (int mt = 0; mt < 4; mt++)
#pragma unroll
    for (int nt = 0; nt < 2; nt++) acc[mt][nt] = zero;

  const unsigned short* ap = xb + (size_t)(m0 + srow) * D_ + skc;
  const unsigned short* bp = wt + (size_t)(n0 + srow) * D_ + skc;
  gl_lds16(ap,      smem + tid * 8);
  gl_lds16(bp,      smem + 12288 + tid * 8);
  gl_lds16(ap + 32, smem + 4096 + tid * 8);
  gl_lds16(bp + 32, smem + 12288 + 4096 + tid * 8);

  int bc = 0;                                      // current buffer = it % 3
  for (int it = 0; it < 32; it++) {
    if (it < 31) bar_vm2(); else bar_vm0();        // retire batch `it`; keep batch it+1 flying
    if (it + 2 < 32) {
      int bn_ = bc < 1 ? bc + 2 : bc - 1;          // (it+2) % 3
      gl_lds16(ap + (it + 2) * 32, smem + bn_ * 4096 + tid * 8);
      gl_lds16(bp + (it + 2) * 32, smem + 12288 + bn_ * 4096 + tid * 8);
    }
    const unsigned short* Ab = smem + bc * 4096;
    const unsigned short* Bb = smem + 12288 + bc * 4096;
    bf16x8 af[4], bfv[2];
#pragma unroll
    for (int mt = 0; mt < 4; mt++) af[mt]  = *(const bf16x8*)(Ab + (wm * 64 + mt * 16 + l15) * 32 + q4 * 8);
#pragma unroll
    for (int nt = 0; nt < 2; nt++) bfv[nt] = *(const bf16x8*)(Bb + (wn * 32 + nt * 16 + l15) * 32 + q4 * 8);
#pragma unroll
    for (int mt = 0; mt < 4; mt++)
#pragma unroll
      for (int nt = 0; nt < 2; nt++)
        acc[mt][nt] = __builtin_amdgcn_mfma_f32_16x16x32_bf16(af[mt], bfv[nt], acc[mt][nt], 0, 0, 0);
    bc = bc == 2 ? 0 : bc + 1;
  }

  if (blockIdx.z < 2) {
    // Q/K: store [B,H,S,HD]
#pragma unroll
    for (int nt = 0; nt < 2; nt++) {
      int n = n0 + wn * 32 + nt * 16 + l15;
      float bn = bias[n];
      int h = n >> 6, hd = n & 63;
#pragma unroll
      for (int mt = 0; mt < 4; mt++) {
#pragma unroll
        for (int r = 0; r < 4; r++) {
          int m = m0 + wm * 64 + mt * 16 + q4 * 4 + r;   // C row = quad*4 + reg
          int b = m >> 11, s = m & (S_ - 1);
          out[(((size_t)(b * H_ + h)) * S_ + s) * HD_ + hd] = f2b((acc[mt][nt][r] + bn) * scl);
        }
      }
    }
  } else {
    // V: transpose via LDS (64x136 pad), store [B,H,HD,S] coalesced; packed b64 writes
    unsigned short* buf = smem;                         // 8704 shorts < 24576
#pragma unroll
    for (int p = 0; p < 2; p++) {                       // n-half: wn in {2p, 2p+1}
      __syncthreads();
      if ((wn >> 1) == p) {
#pragma unroll
        for (int nt = 0; nt < 2; nt++) {
          int np = (wn & 1) * 32 + nt * 16 + l15;       // n' in [0,64)
          float bn = bias[n0 + p * 64 + np];
#pragma unroll
          for (int mt = 0; mt < 4; mt++) {
            f32x4 vb = acc[mt][nt];
            vb[0] += bn; vb[1] += bn; vb[2] += bn; vb[3] += bn;
            bf16x4 pk = __builtin_convertvector(vb, bf16x4);
            *(bf16x4*)(&buf[np * 136 + wm * 64 + mt * 16 + q4 * 4]) = pk;
          }
        }
      }
      __syncthreads();
#pragma unroll
      for (int i = 0; i < 2; i++) {
        int ci = tid + i * 512;                      // 1024 chunks of 8
        int np = ci >> 4, c = ci & 15;
        int n = n0 + p * 64 + np;
        int h = n >> 6, hd = n & 63;
        int m = m0 + c * 8;
        int b = m >> 11, s = m & (S_ - 1);
        *(uint4*)(out + (((size_t)(b * H_ + h)) * HD_ + hd) * S_ + s) = *(const uint4*)(buf + np * 136 + c * 8);
      }
    }
  }
}

// ---------------------------------------------------------------- flash attention (S^T form)
// 256 blocks x 1024 threads (16 waves = 4 waves/SIMD, the latency-hiding fix).
// Block = one bh, q-tile pair {x, 15-x} (sequential halves). Within a half, wave-pairs
// split the k-tile stream: waves 0-7 (lo) process even k-tiles, waves 8-15 (hi) odd
// k-tiles of the SAME q rows, each with private online-softmax state; states are merged
// once per half via LDS (LSE merge). Every block runs exactly
// ceil((x+1)/2)+ceil((16-x)/2) = 9 barrier steps -> perfect balance, 2 k-tiles/barrier.
// K/V LDS XOR-swizzled (no pads, read-XOR is per-thread constant); P staged per-32-key
// slice ([16][40]/wave). LDS total 151,552 B (1 block/CU, 16 waves).
// bh -> XCD clustering: blockIdx % 8 == bh % 8, so one head's 8 blocks share one L2.
__global__ __launch_bounds__(1024, 4) void attn_kernel(
    const unsigned short* __restrict__ Q, const unsigned short* __restrict__ K,
    const unsigned short* __restrict__ Vt_g, unsigned short* __restrict__ O) {
  const int id = blockIdx.x;
  const int bh = id & 31, x = id >> 5;          // id%8 == bh%8 -> same-XCD L2 reuse per head
  const int b = bh >> 4, h = bh & 15;
  const unsigned short* Qh = Q    + (size_t)bh * S_ * HD_;
  const unsigned short* Kh = K    + (size_t)bh * S_ * HD_;
  const unsigned short* Vh = Vt_g + (size_t)bh * HD_ * S_;   // [HD][S]

  __shared__ __align__(16) unsigned short Ks[2][2][128 * 64]; // [buf][slot][key][hd^swz] 64 KB
  __shared__ __align__(16) unsigned short Vt[2][2][64 * 128]; // [buf][slot][hd][key^swz] 64 KB
  __shared__ __align__(16) unsigned short Ps[16][640];        // per-wave P slice [q][40] 20 KB

  const int tid = threadIdx.x, lane = tid & 63, w = tid >> 6;
  const int hi = w >> 3, qw = w & 7;            // wave pair (qw): lo=even k-tiles, hi=odd
  const int l15 = lane & 15, q4 = lane >> 4;
  const int st = tid >> 9, sid = tid & 511;     // staging half: threads st=0 stage slot0, st=1 slot1
  const int krow0 = sid >> 3, kcol0 = (sid & 7) * 8;
  const int vrow0 = sid >> 4, vcol0 = (sid & 15) * 8;
  const int kc0s = kcol0 ^ ((krow0 & 7) << 3);  // swizzled staging cols (row-constant XOR)
  const int vc0s = vcol0 ^ ((vrow0 & 7) << 3);
  const int kx = (l15 & 7) << 3;                // frag-read XOR (constant per thread)
  const int kcA = (q4 * 8) ^ kx, kcB = (q4 * 8 + 32) ^ kx;
  unsigned short* Pw = &Ps[w][0];
  const int pw0 = l15 * 40 + q4 * 4;
  const int pr0 = l15 * 40 + q4 * 8;
  float* scr = (float*)&Ks[0][0][0];            // merge scratch (barrier-fenced reuse)
  float* sp = scr + (size_t)(qw * 64 + lane) * 20;

  f32x4 zero = {0.f, 0.f, 0.f, 0.f};
  int stc = 0;                                  // step counter (buffer parity across halves)

  for (int hf = 0; hf < 2; hf++) {
    const int qi = hf ? 15 - x : x;
    const int q0 = qi * 128;
    const int nkt = qi + 1, nst = (nkt + 1) >> 1;

    // Q B-frags direct from global (both partner waves load same rows; cached)
    const unsigned short* qp = Qh + (size_t)(q0 + qw * 16 + l15) * HD_ + q4 * 8;
    bf16x8 bq0 = *(const bf16x8*)(qp);
    bf16x8 bq1 = *(const bf16x8*)(qp + 32);
    const int qrow = q0 + qw * 16 + l15;

    float m_i = -1e30f, l_i = 0.f;
    f32x4 o_acc[4];
#pragma unroll
    for (int t4 = 0; t4 < 4; t4++) o_acc[t4] = zero;

    // prefetch step-0 tiles (st-th tile) into regs
    uint4 kp0 = {0,0,0,0}, kp1 = {0,0,0,0}, vp0 = {0,0,0,0}, vp1 = {0,0,0,0};
    if (st < nkt) {
      const int k0p = st * 128;
      kp0 = *(const uint4*)(Kh + (size_t)(k0p + krow0) * HD_ + kcol0);
      kp1 = *(const uint4*)(Kh + (size_t)(k0p + krow0 + 64) * HD_ + kcol0);
      vp0 = *(const uint4*)(Vh + (size_t)vrow0 * S_ + k0p + vcol0);
      vp1 = *(const uint4*)(Vh + (size_t)(vrow0 + 32) * S_ + k0p + vcol0);
    }

    for (int s = 0; s < nst; s++, stc++) {
      const int buf = stc & 1;
      {
        unsigned short* Kb = &Ks[buf][st][0];
        unsigned short* Vb = &Vt[buf][st][0];
        *(uint4*)(Kb + krow0 * 64 + kc0s) = kp0;          // stale regs for invalid tiles are
        *(uint4*)(Kb + (krow0 + 64) * 64 + kc0s) = kp1;   // written but never read
        *(uint4*)(Vb + vrow0 * 128 + vc0s) = vp0;
        *(uint4*)(Vb + (vrow0 + 32) * 128 + vc0s) = vp1;
      }
      bar_lgkm();                                  // barrier WITHOUT vmcnt drain
      const int ktn = 2 * (s + 1) + st;            // next-step prefetch (stays in flight)
      if (ktn < nkt) {
        const int k0n = ktn * 128;
        kp0 = *(const uint4*)(Kh + (size_t)(k0n + krow0) * HD_ + kcol0);
        kp1 = *(const uint4*)(Kh + (size_t)(k0n + krow0 + 64) * HD_ + kcol0);
        vp0 = *(const uint4*)(Vh + (size_t)vrow0 * S_ + k0n + vcol0);
        vp1 = *(const uint4*)(Vh + (size_t)(vrow0 + 32) * S_ + k0n + vcol0);
      }

      const int kt = 2 * s + hi;                   // this wave's k-tile
      if (kt < nkt) {
        const int k0 = kt * 128;
        const unsigned short* Kb = &Ks[buf][hi][0];
        const unsigned short* Vb = &Vt[buf][hi][0];

        // S^T = K.Q^T : A = K-frag (m=key), B = Q-frag (n=q); Q pre-scaled by SC_LOG2E
        f32x4 sc[8];
#pragma unroll
        for (int nt = 0; nt < 8; nt++) sc[nt] = zero;
        __builtin_amdgcn_s_setprio(1);
#pragma unroll
        for (int nt = 0; nt < 8; nt++) {
          bf16x8 ak0 = *(const bf16x8*)(Kb + (nt * 16 + l15) * 64 + kcA);
          bf16x8 ak1 = *(const bf16x8*)(Kb + (nt * 16 + l15) * 64 + kcB);
          sc[nt] = __builtin_amdgcn_mfma_f32_16x16x32_bf16(ak0, bq0, sc[nt], 0, 0, 0);
          sc[nt] = __builtin_amdgcn_mfma_f32_16x16x32_bf16(ak1, bq1, sc[nt], 0, 0, 0);
        }
        __builtin_amdgcn_s_setprio(0);

        // causal mask (diagonal tile only)
        if ((k0 + 127) > (q0 + qw * 16)) {
#pragma unroll
          for (int nt = 0; nt < 8; nt++)
#pragma unroll
            for (int r = 0; r < 4; r++) {
              int key = k0 + nt * 16 + q4 * 4 + r;
              if (key > qrow) sc[nt][r] = -1e30f;
            }
        }

        // tree max (depth ~6 instead of 32-deep serial chain)
        float am[8];
#pragma unroll
        for (int nt = 0; nt < 8; nt++)
          am[nt] = fmaxf(fmaxf(sc[nt][0], sc[nt][1]), fmaxf(sc[nt][2], sc[nt][3]));
#pragma unroll
        for (int sr = 4; sr > 0; sr >>= 1)
#pragma unroll
          for (int i2 = 0; i2 < sr; i2++) am[i2] = fmaxf(am[i2], am[i2 + sr]);
        float mx = am[0];
        mx = fmaxf(mx, __shfl_xor(mx, 16));
        mx = fmaxf(mx, __shfl_xor(mx, 32));
        mx = fmaxf(mx, m_i);

        // T13 defer-max: skip O-rescale while tile max grows < 2^10 (log2 domain)
        if (!__all(mx - m_i <= 10.0f)) {
          float alpha = __builtin_amdgcn_exp2f(m_i - mx);
          m_i = mx;
          l_i *= alpha;
#pragma unroll
          for (int r = 0; r < 4; r++) {
            float ar = __shfl(alpha, q4 * 4 + r);
            o_acc[0][r] *= ar; o_acc[1][r] *= ar; o_acc[2][r] *= ar; o_acc[3][r] *= ar;
          }
        }

        // exp2 + tree sum
        float sm[8];
#pragma unroll
        for (int nt = 0; nt < 8; nt++) {
          f32x4 pv;
#pragma unroll
          for (int r = 0; r < 4; r++) pv[r] = __builtin_amdgcn_exp2f(sc[nt][r] - m_i);
          sc[nt] = pv;
          sm[nt] = (pv[0] + pv[1]) + (pv[2] + pv[3]);
        }
#pragma unroll
        for (int sr = 4; sr > 0; sr >>= 1)
#pragma unroll
          for (int i2 = 0; i2 < sr; i2++) sm[i2] += sm[i2 + sr];
        float rs = sm[0];
        rs += __shfl_xor(rs, 16);
        rs += __shfl_xor(rs, 32);
        l_i += rs;

        // O += P V, per-32-key slice: stage P^T slice (wave-local) then 4 MFMA
#pragma unroll
        for (int ks = 0; ks < 4; ks++) {
          bf16x4 pk0 = __builtin_convertvector(sc[2 * ks],     bf16x4);
          bf16x4 pk1 = __builtin_convertvector(sc[2 * ks + 1], bf16x4);
          *(bf16x4*)(Pw + pw0)      = pk0;
          *(bf16x4*)(Pw + pw0 + 16) = pk1;
          __threadfence_block();                  // wave-local LDS write->read ordering
          bf16x8 ap2 = *(const bf16x8*)(Pw + pr0);
          __builtin_amdgcn_s_setprio(1);
#pragma unroll
          for (int nt2 = 0; nt2 < 4; nt2++) {
            bf16x8 bv = *(const bf16x8*)(Vb + (nt2 * 16 + l15) * 128 + ((ks * 32 + q4 * 8) ^ kx));
            o_acc[nt2] = __builtin_amdgcn_mfma_f32_16x16x32_bf16(ap2, bv, o_acc[nt2], 0, 0, 0);
          }
          __builtin_amdgcn_s_setprio(0);
        }
      }
    }

    // --- merge wave-pair states (LSE merge) + epilogue; scratch reuses Ks (barrier-fenced)
    bar_lgkm();                                   // all compute done -> Ks reusable
    if (hi) {
      *(f32x4*)(sp + 0)  = o_acc[0];
      *(f32x4*)(sp + 4)  = o_acc[1];
      *(f32x4*)(sp + 8)  = o_acc[2];
      *(f32x4*)(sp + 12) = o_acc[3];
      sp[16] = m_i; sp[17] = l_i;
    }
    bar_lgkm();
    if (!hi) {
      f32x4 oh[4];
      oh[0] = *(const f32x4*)(sp + 0);
      oh[1] = *(const f32x4*)(sp + 4);
      oh[2] = *(const f32x4*)(sp + 8);
      oh[3] = *(const f32x4*)(sp + 12);
      float m_h = sp[16], l_h = sp[17];
      float M   = fmaxf(m_i, m_h);
      float a_l = __builtin_amdgcn_exp2f(m_i - M);
      float a_h = __builtin_amdgcn_exp2f(m_h - M);
      float l_f = l_i * a_l + l_h * a_h;
#pragma unroll
      for (int r = 0; r < 4; r++) {
        float arl = __shfl(a_l, q4 * 4 + r);
        float arh = __shfl(a_h, q4 * 4 + r);
        float inv = 1.0f / __shfl(l_f, q4 * 4 + r);
        int s_ = q0 + qw * 16 + q4 * 4 + r;
#pragma unroll
        for (int nt2 = 0; nt2 < 4; nt2++)
          O[((size_t)(b * S_ + s_)) * D_ + h * HD_ + nt2 * 16 + l15] =
              f2b((o_acc[nt2][r] * arl + oh[nt2][r] * arh) * inv);
      }
    }
    bar_lgkm();                                   // merge reads done -> next half may stage
  }
}

// ---------------------------------------------------------------- output GEMM
// Same 512-thread shape as qkv; triple-buffer + vmcnt(2) barriers; fp32 out.
__global__ __launch_bounds__(512) void out_gemm_kernel(
    const unsigned short* __restrict__ ab, const unsigned short* __restrict__ wot,
    const float* __restrict__ bo, float* __restrict__ out) {
  __shared__ __align__(16) unsigned short smem[6 * 4096];   // 48 KB
  const int tid = threadIdx.x;
  const int lane = tid & 63, wid = tid >> 6;
  const int wm = wid & 1, wn = wid >> 1;
  const int m0 = blockIdx.x * 128, n0 = blockIdx.y * 128;
  const int l15 = lane & 15, q4 = lane >> 4;
  const int srow = tid >> 2, skc = (tid & 3) * 8;

  f32x4 zero = {0.f, 0.f, 0.f, 0.f};
  f32x4 acc[4][2];
#pragma unroll
  for (int mt = 0; mt < 4; mt++)
#pragma unroll
    for (int nt = 0; nt < 2; nt++) acc[mt][nt] = zero;

  const unsigned short* ap = ab  + (size_t)(m0 + srow) * D_ + skc;
  const unsigned short* bp = wot + (size_t)(n0 + srow) * D_ + skc;
  gl_lds16(ap,      smem + tid * 8);
  gl_lds16(bp,      smem + 12288 + tid * 8);
  gl_lds16(ap + 32, smem + 4096 + tid * 8);
  gl_lds16(bp + 32, smem + 12288 + 4096 + tid * 8);

  int bc = 0;
  for (int it = 0; it < 32; it++) {
    if (it < 31) bar_vm2(); else bar_vm0();
    if (it + 2 < 32) {
      int bn_ = bc < 1 ? bc + 2 : bc - 1;
      gl_lds16(ap + (it + 2) * 32, smem + bn_ * 4096 + tid * 8);
      gl_lds16(bp + (it + 2) * 32, smem + 12288 + bn_ * 4096 + tid * 8);
    }
    const unsigned short* Ab = smem + bc * 4096;
    const unsigned short* Bb = smem + 12288 + bc * 4096;
    bf16x8 af[4], bfv[2];
#pragma unroll
    for (int mt = 0; mt < 4; mt++) af[mt]  = *(const bf16x8*)(Ab + (wm * 64 + mt * 16 + l15) * 32 + q4 * 8);
#pragma unroll
    for (int nt = 0; nt < 2; nt++) bfv[nt] = *(const bf16x8*)(Bb + (wn * 32 + nt * 16 + l15) * 32 + q4 * 8);
#pragma unroll
    for (int mt = 0; mt < 4; mt++)
#pragma unroll
      for (int nt = 0; nt < 2; nt++)
        acc[mt][nt] = __builtin_amdgcn_mfma_f32_16x16x32_bf16(af[mt], bfv[nt], acc[mt][nt], 0, 0, 0);
    bc = bc == 2 ? 0 : bc + 1;
  }

#pragma unroll
  for (int nt = 0; nt < 2; nt++) {
    int n = n0 + wn * 32 + nt * 16 + l15;
    float bn = bo[n];
#pragma unroll
    for (int mt = 0; mt < 4; mt++) {
#pragma unroll
      for (int r = 0; r < 4; r++) {
        int m = m0 + wm * 64 + mt * 16 + q4 * 4 + r;
        out[(size_t)m * D_ + n] = acc[mt][nt][r] + bn;
      }
    }
  }
}

// ---------------------------------------------------------------- launch
extern "C" void kernel_launch(void* const* d_in, const int* in_sizes, int n_in,
                              void* d_out, int out_size, void* d_ws, size_t ws_size,
                              hipStream_t stream) {
  const float* x  = (const float*)d_in[0];
  const float* wq = (const float*)d_in[1];
  const float* bq = (const float*)d_in[2];
  const float* wk = (const float*)d_in[3];
  const float* bk = (const float*)d_in[4];
  const float* wv = (const float*)d_in[5];
  const float* bv = (const float*)d_in[6];
  const float* wo = (const float*)d_in[7];
  const float* bo = (const float*)d_in[8];
  float* out = (float*)d_out;

  char* ws = (char*)d_ws;
  unsigned short* xb  = (unsigned short*)(ws);               // 8 MB; reused as attn out
  unsigned short* wqt = (unsigned short*)(ws + (8u  << 20));
  unsigned short* wkt = (unsigned short*)(ws + (10u << 20));
  unsigned short* wvt = (unsigned short*)(ws + (12u << 20));
  unsigned short* wot = (unsigned short*)(ws + (14u << 20));
  unsigned short* qb  = (unsigned short*)(ws + (16u << 20)); // [B,H,S,HD] bf16 (pre-scaled)
  unsigned short* kb  = (unsigned short*)(ws + (24u << 20)); // [B,H,S,HD] bf16
  unsigned short* vtg = (unsigned short*)(ws + (32u << 20)); // [B,H,HD,S] bf16 (transposed V)
  unsigned short* ab  = xb;                                  // attention output [B,S,D] bf16

  cvt_all_kernel<<<dim3(32, 32, 5), dim3(32, 8), 0, stream>>>(x, wq, wk, wv, wo, xb, wqt, wkt, wvt, wot);
  qkv_gemm_kernel<<<dim3(32, 8, 3), dim3(512), 0, stream>>>(xb, wqt, wkt, wvt, bq, bk, bv, qb, kb, vtg);
  attn_kernel<<<dim3(256), dim3(1024), 0, stream>>>(qb, kb, vtg, ab);
  out_gemm_kernel<<<dim3(32, 8), dim3(512), 0, stream>>>(ab, wot, bo, out);
}

// Round 2
// 177.068 us; speedup vs baseline: 1.0182x; 1.0171x over previous
//
#include <hip/hip_runtime.h>
#include <hip/hip_bf16.h>
#include <cstdint>

#define B_  2
#define S_  2048
#define D_  1024
#define H_  16
#define HD_ 64
#define M_  (B_ * S_)   // 4096
static constexpr float SC_LOG2E = 0.125f * 1.44269504088896f;  // SCALE * log2(e), folded into Q

typedef __bf16 bf16x8 __attribute__((ext_vector_type(8)));
typedef __bf16 bf16x4 __attribute__((ext_vector_type(4)));
typedef float  f32x4  __attribute__((ext_vector_type(4)));

__device__ __forceinline__ unsigned short f2b(float f) {
  union { float f; unsigned u; } x; x.f = f;
  unsigned r = x.u + 0x7FFF + ((x.u >> 16) & 1);   // RNE
  return (unsigned short)(r >> 16);
}

// async global->LDS, 16B per lane; HW uses wave-uniform LDS base + lane*16
__device__ __forceinline__ void gl_lds16(const unsigned short* g, unsigned short* l) {
  __builtin_amdgcn_global_load_lds((const __attribute__((address_space(1))) void*)g,
                                   (__attribute__((address_space(3))) void*)l, 16, 0, 0);
}

// Barriers that do NOT drain vmcnt(0) (unlike __syncthreads) — keep global loads in flight.
__device__ __forceinline__ void bar_lgkm() {   // LDS-producer barrier
  asm volatile("s_waitcnt lgkmcnt(0)\n\ts_barrier" ::: "memory");
}
__device__ __forceinline__ void bar_vm2() {    // retire all but 2 newest vmem (AITER-style)
  asm volatile("s_waitcnt vmcnt(2) lgkmcnt(0)\n\ts_barrier" ::: "memory");
}
__device__ __forceinline__ void bar_vm0() {    // full drain
  asm volatile("s_waitcnt vmcnt(0) lgkmcnt(0)\n\ts_barrier" ::: "memory");
}

// ------------------------------------------- fused cvt: z<4 -> transpose+cvt W, z==4 -> cvt x
__global__ void cvt_all_kernel(const float* __restrict__ x,
                               const float* __restrict__ w0, const float* __restrict__ w1,
                               const float* __restrict__ w2, const float* __restrict__ w3,
                               unsigned short* __restrict__ xb,
                               unsigned short* __restrict__ o0, unsigned short* __restrict__ o1,
                               unsigned short* __restrict__ o2, unsigned short* __restrict__ o3) {
  int tx = threadIdx.x, ty = threadIdx.y;
  if (blockIdx.z == 4) {
    int tid = ty * 32 + tx;
    int base = ((int)blockIdx.y * 32 + (int)blockIdx.x) * 1024 + tid;  // f4 index
    const float4* xf = (const float4*)x;
    ushort4* ob = (ushort4*)xb;
#pragma unroll
    for (int j = 0; j < 4; j++) {
      float4 v = xf[base + j * 256];
      ushort4 r;
      r.x = f2b(v.x); r.y = f2b(v.y); r.z = f2b(v.z); r.w = f2b(v.w);
      ob[base + j * 256] = r;
    }
    return;
  }
  const float* w = blockIdx.z == 0 ? w0 : blockIdx.z == 1 ? w1 : blockIdx.z == 2 ? w2 : w3;
  unsigned short* o = blockIdx.z == 0 ? o0 : blockIdx.z == 1 ? o1 : blockIdx.z == 2 ? o2 : o3;
  __shared__ float t[32][33];
  int x0 = blockIdx.x * 32, y0 = blockIdx.y * 32;
#pragma unroll
  for (int j = 0; j < 4; j++)
    t[ty + j * 8][tx] = w[(size_t)(y0 + ty + j * 8) * D_ + x0 + tx];
  __syncthreads();
#pragma unroll
  for (int j = 0; j < 4; j++)
    o[(size_t)(x0 + ty + j * 8) * D_ + y0 + tx] = f2b(t[tx][ty + j * 8]);
}

// ---------------------------------------------------------------- QKV GEMM
// 512 threads = 8 waves (2x4 wave grid, wave tile 64x32); 128x128 block tile, BK=32.
// TRIPLE-buffered global_load_lds staging; barrier = s_waitcnt vmcnt(2) (not 0!).
__global__ __launch_bounds__(512) void qkv_gemm_kernel(
    const unsigned short* __restrict__ xb,
    const unsigned short* __restrict__ wqt, const unsigned short* __restrict__ wkt,
    const unsigned short* __restrict__ wvt,
    const float* __restrict__ bq, const float* __restrict__ bk, const float* __restrict__ bv,
    unsigned short* __restrict__ qo, unsigned short* __restrict__ ko, unsigned short* __restrict__ vo) {
  const unsigned short* wt = blockIdx.z == 0 ? wqt : blockIdx.z == 1 ? wkt : wvt;
  const float* bias        = blockIdx.z == 0 ? bq  : blockIdx.z == 1 ? bk  : bv;
  unsigned short* out      = blockIdx.z == 0 ? qo  : blockIdx.z == 1 ? ko  : vo;
  const float scl = blockIdx.z == 0 ? SC_LOG2E : 1.0f;

  __shared__ __align__(16) unsigned short smem[6 * 4096];   // 48 KB
  const int tid = threadIdx.x;
  const int lane = tid & 63, wid = tid >> 6;
  const int wm = wid & 1, wn = wid >> 1;          // 2 x 4 wave grid
  const int m0 = blockIdx.x * 128, n0 = blockIdx.y * 128;
  const int l15 = lane & 15, q4 = lane >> 4;
  const int srow = tid >> 2, skc = (tid & 3) * 8; // staging slot: 512 chunks, 1/thread

  f32x4 zero = {0.f, 0.f, 0.f, 0.f};
  f32x4 acc[4][2];
#pragma unroll
  for (int mt = 0; mt < 4; mt++)
#pragma unroll
    for (int nt = 0; nt < 2; nt++) acc[mt][nt] = zero;

  const unsigned short* ap = xb + (size_t)(m0 + srow) * D_ + skc;
  const unsigned short* bp = wt + (size_t)(n0 + srow) * D_ + skc;
  gl_lds16(ap,      smem + tid * 8);
  gl_lds16(bp,      smem + 12288 + tid * 8);
  gl_lds16(ap + 32, smem + 4096 + tid * 8);
  gl_lds16(bp + 32, smem + 12288 + 4096 + tid * 8);

  int bc = 0;                                      // current buffer = it % 3
  for (int it = 0; it < 32; it++) {
    if (it < 31) bar_vm2(); else bar_vm0();        // retire batch `it`; keep batch it+1 flying
    if (it + 2 < 32) {
      int bn_ = bc < 1 ? bc + 2 : bc - 1;          // (it+2) % 3
      gl_lds16(ap + (it + 2) * 32, smem + bn_ * 4096 + tid * 8);
      gl_lds16(bp + (it + 2) * 32, smem + 12288 + bn_ * 4096 + tid * 8);
    }
    const unsigned short* Ab = smem + bc * 4096;
    const unsigned short* Bb = smem + 12288 + bc * 4096;
    bf16x8 af[4], bfv[2];
#pragma unroll
    for (int mt = 0; mt < 4; mt++) af[mt]  = *(const bf16x8*)(Ab + (wm * 64 + mt * 16 + l15) * 32 + q4 * 8);
#pragma unroll
    for (int nt = 0; nt < 2; nt++) bfv[nt] = *(const bf16x8*)(Bb + (wn * 32 + nt * 16 + l15) * 32 + q4 * 8);
#pragma unroll
    for (int mt = 0; mt < 4; mt++)
#pragma unroll
      for (int nt = 0; nt < 2; nt++)
        acc[mt][nt] = __builtin_amdgcn_mfma_f32_16x16x32_bf16(af[mt], bfv[nt], acc[mt][nt], 0, 0, 0);
    bc = bc == 2 ? 0 : bc + 1;
  }

  if (blockIdx.z < 2) {
    // Q/K: store [B,H,S,HD]
#pragma unroll
    for (int nt = 0; nt < 2; nt++) {
      int n = n0 + wn * 32 + nt * 16 + l15;
      float bn = bias[n];
      int h = n >> 6, hd = n & 63;
#pragma unroll
      for (int mt = 0; mt < 4; mt++) {
#pragma unroll
        for (int r = 0; r < 4; r++) {
          int m = m0 + wm * 64 + mt * 16 + q4 * 4 + r;   // C row = quad*4 + reg
          int b = m >> 11, s = m & (S_ - 1);
          out[(((size_t)(b * H_ + h)) * S_ + s) * HD_ + hd] = f2b((acc[mt][nt][r] + bn) * scl);
        }
      }
    }
  } else {
    // V: transpose via LDS (64x136 pad), store [B,H,HD,S] coalesced; packed b64 writes
    unsigned short* buf = smem;                         // 8704 shorts < 24576
#pragma unroll
    for (int p = 0; p < 2; p++) {                       // n-half: wn in {2p, 2p+1}
      __syncthreads();
      if ((wn >> 1) == p) {
#pragma unroll
        for (int nt = 0; nt < 2; nt++) {
          int np = (wn & 1) * 32 + nt * 16 + l15;       // n' in [0,64)
          float bn = bias[n0 + p * 64 + np];
#pragma unroll
          for (int mt = 0; mt < 4; mt++) {
            f32x4 vb = acc[mt][nt];
            vb[0] += bn; vb[1] += bn; vb[2] += bn; vb[3] += bn;
            bf16x4 pk = __builtin_convertvector(vb, bf16x4);
            *(bf16x4*)(&buf[np * 136 + wm * 64 + mt * 16 + q4 * 4]) = pk;
          }
        }
      }
      __syncthreads();
#pragma unroll
      for (int i = 0; i < 2; i++) {
        int ci = tid + i * 512;                      // 1024 chunks of 8
        int np = ci >> 4, c = ci & 15;
        int n = n0 + p * 64 + np;
        int h = n >> 6, hd = n & 63;
        int m = m0 + c * 8;
        int b = m >> 11, s = m & (S_ - 1);
        *(uint4*)(out + (((size_t)(b * H_ + h)) * HD_ + hd) * S_ + s) = *(const uint4*)(buf + np * 136 + c * 8);
      }
    }
  }
}

// ---------------------------------------------------------------- flash attention (S^T form)
// 256 blocks x 512 threads = 8 waves. Wave handles 32 q-rows (2 q-groups of 16) -> only
// 4 waves share each K/V tile => LDS frag re-read traffic HALVED vs wave-q-16, and the
// two independent q-group streams give 2-way ILP inside the softmax phase (fills the
// exp2/shfl dependency stalls that made pipes run serially: VALU 33% + MFMA 14% + LDS
// ~40% summed to ~100% of step time with no overlap).
// Waves: qw = w&3 (q-group of 32 rows), hi = w>>2 (k-parity: lo=even, hi=odd k-tiles).
// Staging now via global_load_lds with PRE-SWIZZLED GLOBAL source (m173 pattern): LDS
// dest is linear lane*16B, the XOR swizzle is applied to the global column so readers
// use the same XOR as before. Removes all staging ds_writes + 32 VGPR of reg prefetch.
// One bar_vm0 per step; loads issued at step start have a full step (~9k cy) to land.
// Per-block steps: ceil((x+1)/2)+ceil((16-x)/2) = 9 uniformly.
__global__ __launch_bounds__(512) void attn_kernel(
    const unsigned short* __restrict__ Q, const unsigned short* __restrict__ K,
    const unsigned short* __restrict__ Vt_g, unsigned short* __restrict__ O) {
  const int id = blockIdx.x;
  const int bh = id & 31, x = id >> 5;          // id%8 == bh%8 -> same-XCD L2 reuse per head
  const int b = bh >> 4, h = bh & 15;
  const unsigned short* Qh = Q    + (size_t)bh * S_ * HD_;
  const unsigned short* Kh = K    + (size_t)bh * S_ * HD_;
  const unsigned short* Vh = Vt_g + (size_t)bh * HD_ * S_;   // [HD][S]

  __shared__ __align__(16) unsigned short Ks[2][2][128 * 64]; // [buf][slot][key][hd^swz] 64 KB
  __shared__ __align__(16) unsigned short Vt[2][2][64 * 128]; // [buf][slot][hd][key^swz] 64 KB
  __shared__ __align__(16) unsigned short Ps[8][1280];        // per-wave P slice [32 q][40] 20 KB

  const int tid = threadIdx.x, lane = tid & 63, w = tid >> 6;
  const int hi = w >> 2, qw = w & 3;            // k-parity / q-group (32 rows)
  const int l15 = lane & 15, q4 = lane >> 4;
  const int kx = (l15 & 7) << 3;                // frag-read XOR (constant per thread)
  const int kcA = (q4 * 8) ^ kx, kcB = (q4 * 8 + 32) ^ kx;
  unsigned short* Pw = &Ps[w][0];
  float* scr = (float*)&Ks[0][0][0];            // merge scratch (barrier-fenced reuse)
  float* sp = scr + (size_t)(qw * 64 + lane) * 36;

  // staging source pointers: pre-swizzled global columns, linear LDS dest (lane*16B)
  const unsigned short* kg[2];
  const unsigned short* vg[2];
#pragma unroll
  for (int j = 0; j < 2; j++) {
    int li = tid + j * 512;
    int krow = li >> 3;
    int kcol = ((tid & 7) * 8) ^ ((krow & 7) * 8);
    kg[j] = Kh + (size_t)krow * HD_ + kcol;     // + k0*HD_ at use
    int vrow = li >> 4;
    int vcol = ((tid & 15) * 8) ^ ((vrow & 7) * 8);
    vg[j] = Vh + (size_t)vrow * S_ + vcol;      // + k0 at use
  }

  f32x4 zero = {0.f, 0.f, 0.f, 0.f};
  int stc = 0;                                  // step counter (buffer parity across halves)

  for (int hf = 0; hf < 2; hf++) {
    const int qi = hf ? 15 - x : x;
    const int q0 = qi * 128;
    const int nkt = qi + 1, nst = (nkt + 1) >> 1;

    // Q B-frags direct from global, 2 q-groups of 16 rows
    bf16x8 bq[2][2];
#pragma unroll
    for (int g = 0; g < 2; g++) {
      const unsigned short* qp = Qh + (size_t)(q0 + qw * 32 + g * 16 + l15) * HD_ + q4 * 8;
      bq[g][0] = *(const bf16x8*)(qp);
      bq[g][1] = *(const bf16x8*)(qp + 32);
    }

    float m_i[2] = {-1e30f, -1e30f}, l_i[2] = {0.f, 0.f};
    f32x4 o_acc[2][4];
#pragma unroll
    for (int g = 0; g < 2; g++)
#pragma unroll
      for (int t4 = 0; t4 < 4; t4++) o_acc[g][t4] = zero;

    // prologue: stage step-0 tiles {0,1} (DMA; tile>=nkt writes garbage, never read)
    {
      const int bufn = stc & 1;
#pragma unroll
      for (int s2 = 0; s2 < 2; s2++) {
        const int k0s = s2 * 128;
        unsigned short* Kd = &Ks[bufn][s2][0];
        unsigned short* Vd = &Vt[bufn][s2][0];
#pragma unroll
        for (int j = 0; j < 2; j++) {
          gl_lds16(kg[j] + (size_t)k0s * HD_, Kd + (tid + j * 512) * 8);
          gl_lds16(vg[j] + k0s,               Vd + (tid + j * 512) * 8);
        }
      }
    }

    for (int s = 0; s < nst; s++, stc++) {
      const int bufc = stc & 1;
      bar_vm0();                                 // own loads landed; prev-buf readers done
      if (s + 1 < nst) {                         // stage next step into other buffer
        const int bufn = bufc ^ 1;
#pragma unroll
        for (int s2 = 0; s2 < 2; s2++) {
          const int k0s = (2 * (s + 1) + s2) * 128;
          unsigned short* Kd = &Ks[bufn][s2][0];
          unsigned short* Vd = &Vt[bufn][s2][0];
#pragma unroll
          for (int j = 0; j < 2; j++) {
            gl_lds16(kg[j] + (size_t)k0s * HD_, Kd + (tid + j * 512) * 8);
            gl_lds16(vg[j] + k0s,               Vd + (tid + j * 512) * 8);
          }
        }
      }

      const int kt = 2 * s + hi;                 // this wave's k-tile
      if (kt < nkt) {
        const int k0 = kt * 128;
        const unsigned short* Kb = &Ks[bufc][hi][0];
        const unsigned short* Vb = &Vt[bufc][hi][0];

        // S^T = K.Q^T : A = K-frag (m=key), B = Q-frags (n=q), both q-groups share ak
        f32x4 sc[2][8];
#pragma unroll
        for (int g = 0; g < 2; g++)
#pragma unroll
          for (int nt = 0; nt < 8; nt++) sc[g][nt] = zero;
        __builtin_amdgcn_s_setprio(1);
#pragma unroll
        for (int nt = 0; nt < 8; nt++) {
          bf16x8 ak0 = *(const bf16x8*)(Kb + (nt * 16 + l15) * 64 + kcA);
          bf16x8 ak1 = *(const bf16x8*)(Kb + (nt * 16 + l15) * 64 + kcB);
          sc[0][nt] = __builtin_amdgcn_mfma_f32_16x16x32_bf16(ak0, bq[0][0], sc[0][nt], 0, 0, 0);
          sc[0][nt] = __builtin_amdgcn_mfma_f32_16x16x32_bf16(ak1, bq[0][1], sc[0][nt], 0, 0, 0);
          sc[1][nt] = __builtin_amdgcn_mfma_f32_16x16x32_bf16(ak0, bq[1][0], sc[1][nt], 0, 0, 0);
          sc[1][nt] = __builtin_amdgcn_mfma_f32_16x16x32_bf16(ak1, bq[1][1], sc[1][nt], 0, 0, 0);
        }
        __builtin_amdgcn_s_setprio(0);

        // softmax per q-group (two independent streams -> VALU ILP)
#pragma unroll
        for (int g = 0; g < 2; g++) {
          const int qrow = q0 + qw * 32 + g * 16 + l15;
          if ((k0 + 127) > (q0 + qw * 32 + g * 16)) {   // diagonal tile: causal mask
#pragma unroll
            for (int nt = 0; nt < 8; nt++)
#pragma unroll
              for (int r = 0; r < 4; r++) {
                int key = k0 + nt * 16 + q4 * 4 + r;
                if (key > qrow) sc[g][nt][r] = -1e30f;
              }
          }
          // tree max
          float am[8];
#pragma unroll
          for (int nt = 0; nt < 8; nt++)
            am[nt] = fmaxf(fmaxf(sc[g][nt][0], sc[g][nt][1]), fmaxf(sc[g][nt][2], sc[g][nt][3]));
#pragma unroll
          for (int sr = 4; sr > 0; sr >>= 1)
#pragma unroll
            for (int i2 = 0; i2 < sr; i2++) am[i2] = fmaxf(am[i2], am[i2 + sr]);
          float mx = am[0];
          mx = fmaxf(mx, __shfl_xor(mx, 16));
          mx = fmaxf(mx, __shfl_xor(mx, 32));
          mx = fmaxf(mx, m_i[g]);

          // T13 defer-max: skip O-rescale while tile max grows < 2^10 (log2 domain)
          if (!__all(mx - m_i[g] <= 10.0f)) {
            float alpha = __builtin_amdgcn_exp2f(m_i[g] - mx);
            m_i[g] = mx;
            l_i[g] *= alpha;
#pragma unroll
            for (int r = 0; r < 4; r++) {
              float ar = __shfl(alpha, q4 * 4 + r);
              o_acc[g][0][r] *= ar; o_acc[g][1][r] *= ar;
              o_acc[g][2][r] *= ar; o_acc[g][3][r] *= ar;
            }
          }

          // exp2 + tree sum
          float sm[8];
#pragma unroll
          for (int nt = 0; nt < 8; nt++) {
            f32x4 pv;
#pragma unroll
            for (int r = 0; r < 4; r++) pv[r] = __builtin_amdgcn_exp2f(sc[g][nt][r] - m_i[g]);
            sc[g][nt] = pv;
            sm[nt] = (pv[0] + pv[1]) + (pv[2] + pv[3]);
          }
#pragma unroll
          for (int sr = 4; sr > 0; sr >>= 1)
#pragma unroll
            for (int i2 = 0; i2 < sr; i2++) sm[i2] += sm[i2 + sr];
          float rs = sm[0];
          rs += __shfl_xor(rs, 16);
          rs += __shfl_xor(rs, 32);
          l_i[g] += rs;
        }

        // O += P V per-32-key slice; V frags shared by both q-groups
#pragma unroll
        for (int ks = 0; ks < 4; ks++) {
#pragma unroll
          for (int g = 0; g < 2; g++) {
            bf16x4 pk0 = __builtin_convertvector(sc[g][2 * ks],     bf16x4);
            bf16x4 pk1 = __builtin_convertvector(sc[g][2 * ks + 1], bf16x4);
            *(bf16x4*)(Pw + (g * 16 + l15) * 40 + q4 * 4)      = pk0;
            *(bf16x4*)(Pw + (g * 16 + l15) * 40 + 16 + q4 * 4) = pk1;
          }
          __threadfence_block();                  // wave-local LDS write->read ordering
          bf16x8 ap0 = *(const bf16x8*)(Pw + l15 * 40 + q4 * 8);
          bf16x8 ap1 = *(const bf16x8*)(Pw + (16 + l15) * 40 + q4 * 8);
          __builtin_amdgcn_s_setprio(1);
#pragma unroll
          for (int nt2 = 0; nt2 < 4; nt2++) {
            bf16x8 bv = *(const bf16x8*)(Vb + (nt2 * 16 + l15) * 128 + ((ks * 32 + q4 * 8) ^ kx));
            o_acc[0][nt2] = __builtin_amdgcn_mfma_f32_16x16x32_bf16(ap0, bv, o_acc[0][nt2], 0, 0, 0);
            o_acc[1][nt2] = __builtin_amdgcn_mfma_f32_16x16x32_bf16(ap1, bv, o_acc[1][nt2], 0, 0, 0);
          }
          __builtin_amdgcn_s_setprio(0);
        }
      }
    }

    // --- merge wave-pair states (LSE merge) + epilogue; scratch reuses Ks (barrier-fenced)
    bar_lgkm();                                   // all compute done -> Ks reusable
    if (hi) {
#pragma unroll
      for (int g = 0; g < 2; g++)
#pragma unroll
        for (int t4 = 0; t4 < 4; t4++) *(f32x4*)(sp + g * 16 + t4 * 4) = o_acc[g][t4];
      sp[32] = m_i[0]; sp[33] = m_i[1];
      sp[34] = l_i[0]; sp[35] = l_i[1];
    }
    bar_lgkm();
    if (!hi) {
#pragma unroll
      for (int g = 0; g < 2; g++) {
        f32x4 oh[4];
#pragma unroll
        for (int t4 = 0; t4 < 4; t4++) oh[t4] = *(const f32x4*)(sp + g * 16 + t4 * 4);
        float m_h = sp[32 + g], l_h = sp[34 + g];
        float M   = fmaxf(m_i[g], m_h);
        float a_l = __builtin_amdgcn_exp2f(m_i[g] - M);
        float a_h = __builtin_amdgcn_exp2f(m_h - M);
        float l_f = l_i[g] * a_l + l_h * a_h;
#pragma unroll
        for (int r = 0; r < 4; r++) {
          float arl = __shfl(a_l, q4 * 4 + r);
          float arh = __shfl(a_h, q4 * 4 + r);
          float inv = 1.0f / __shfl(l_f, q4 * 4 + r);
          int s_ = q0 + qw * 32 + g * 16 + q4 * 4 + r;
#pragma unroll
          for (int nt2 = 0; nt2 < 4; nt2++)
            O[((size_t)(b * S_ + s_)) * D_ + h * HD_ + nt2 * 16 + l15] =
                f2b((o_acc[g][nt2][r] * arl + oh[nt2][r] * arh) * inv);
        }
      }
    }
    bar_lgkm();                                   // merge reads done -> next half may stage
  }
}

// ---------------------------------------------------------------- output GEMM
// Same 512-thread shape as qkv; triple-buffer + vmcnt(2) barriers; fp32 out.
__global__ __launch_bounds__(512) void out_gemm_kernel(
    const unsigned short* __restrict__ ab, const unsigned short* __restrict__ wot,
    const float* __restrict__ bo, float* __restrict__ out) {
  __shared__ __align__(16) unsigned short smem[6 * 4096];   // 48 KB
  const int tid = threadIdx.x;
  const int lane = tid & 63, wid = tid >> 6;
  const int wm = wid & 1, wn = wid >> 1;
  const int m0 = blockIdx.x * 128, n0 = blockIdx.y * 128;
  const int l15 = lane & 15, q4 = lane >> 4;
  const int srow = tid >> 2, skc = (tid & 3) * 8;

  f32x4 zero = {0.f, 0.f, 0.f, 0.f};
  f32x4 acc[4][2];
#pragma unroll
  for (int mt = 0; mt < 4; mt++)
#pragma unroll
    for (int nt = 0; nt < 2; nt++) acc[mt][nt] = zero;

  const unsigned short* ap = ab  + (size_t)(m0 + srow) * D_ + skc;
  const unsigned short* bp = wot + (size_t)(n0 + srow) * D_ + skc;
  gl_lds16(ap,      smem + tid * 8);
  gl_lds16(bp,      smem + 12288 + tid * 8);
  gl_lds16(ap + 32, smem + 4096 + tid * 8);
  gl_lds16(bp + 32, smem + 12288 + 4096 + tid * 8);

  int bc = 0;
  for (int it = 0; it < 32; it++) {
    if (it < 31) bar_vm2(); else bar_vm0();
    if (it + 2 < 32) {
      int bn_ = bc < 1 ? bc + 2 : bc - 1;
      gl_lds16(ap + (it + 2) * 32, smem + bn_ * 4096 + tid * 8);
      gl_lds16(bp + (it + 2) * 32, smem + 12288 + bn_ * 4096 + tid * 8);
    }
    const unsigned short* Ab = smem + bc * 4096;
    const unsigned short* Bb = smem + 12288 + bc * 4096;
    bf16x8 af[4], bfv[2];
#pragma unroll
    for (int mt = 0; mt < 4; mt++) af[mt]  = *(const bf16x8*)(Ab + (wm * 64 + mt * 16 + l15) * 32 + q4 * 8);
#pragma unroll
    for (int nt = 0; nt < 2; nt++) bfv[nt] = *(const bf16x8*)(Bb + (wn * 32 + nt * 16 + l15) * 32 + q4 * 8);
#pragma unroll
    for (int mt = 0; mt < 4; mt++)
#pragma unroll
      for (int nt = 0; nt < 2; nt++)
        acc[mt][nt] = __builtin_amdgcn_mfma_f32_16x16x32_bf16(af[mt], bfv[nt], acc[mt][nt], 0, 0, 0);
    bc = bc == 2 ? 0 : bc + 1;
  }

#pragma unroll
  for (int nt = 0; nt < 2; nt++) {
    int n = n0 + wn * 32 + nt * 16 + l15;
    float bn = bo[n];
#pragma unroll
    for (int mt = 0; mt < 4; mt++) {
#pragma unroll
      for (int r = 0; r < 4; r++) {
        int m = m0 + wm * 64 + mt * 16 + q4 * 4 + r;
        out[(size_t)m * D_ + n] = acc[mt][nt][r] + bn;
      }
    }
  }
}

// ---------------------------------------------------------------- launch
extern "C" void kernel_launch(void* const* d_in, const int* in_sizes, int n_in,
                              void* d_out, int out_size, void* d_ws, size_t ws_size,
                              hipStream_t stream) {
  const float* x  = (const float*)d_in[0];
  const float* wq = (const float*)d_in[1];
  const float* bq = (const float*)d_in[2];
  const float* wk = (const float*)d_in[3];
  const float* bk = (const float*)d_in[4];
  const float* wv = (const float*)d_in[5];
  const float* bv = (const float*)d_in[6];
  const float* wo = (const float*)d_in[7];
  const float* bo = (const float*)d_in[8];
  float* out = (float*)d_out;

  char* ws = (char*)d_ws;
  unsigned short* xb  = (unsigned short*)(ws);               // 8 MB; reused as attn out
  unsigned short* wqt = (unsigned short*)(ws + (8u  << 20));
  unsigned short* wkt = (unsigned short*)(ws + (10u << 20));
  unsigned short* wvt = (unsigned short*)(ws + (12u << 20));
  unsigned short* wot = (unsigned short*)(ws + (14u << 20));
  unsigned short* qb  = (unsigned short*)(ws + (16u << 20)); // [B,H,S,HD] bf16 (pre-scaled)
  unsigned short* kb  = (unsigned short*)(ws + (24u << 20)); // [B,H,S,HD] bf16
  unsigned short* vtg = (unsigned short*)(ws + (32u << 20)); // [B,H,HD,S] bf16 (transposed V)
  unsigned short* ab  = xb;                                  // attention output [B,S,D] bf16

  cvt_all_kernel<<<dim3(32, 32, 5), dim3(32, 8), 0, stream>>>(x, wq, wk, wv, wo, xb, wqt, wkt, wvt, wot);
  qkv_gemm_kernel<<<dim3(32, 8, 3), dim3(512), 0, stream>>>(xb, wqt, wkt, wvt, bq, bk, bv, qb, kb, vtg);
  attn_kernel<<<dim3(256), dim3(512), 0, stream>>>(qb, kb, vtg, ab);
  out_gemm_kernel<<<dim3(32, 8), dim3(512), 0, stream>>>(ab, wot, bo, out);
}